// Round 1
// baseline (320.786 us; speedup 1.0000x reference)
//
#include <hip/hip_runtime.h>
#include <math.h>

#define S_LEN 2048
#define DMODEL 1024
#define NH 16
#define DEPTH 64
#define BATCH 2
#define MTOT (BATCH * S_LEN) // 4096

typedef __attribute__((ext_vector_type(8))) short short8;
typedef __attribute__((ext_vector_type(4))) short short4v;
typedef __attribute__((ext_vector_type(4))) float floatx4;

__device__ __forceinline__ short f2bf(float f) {
    union { float f; unsigned u; } v; v.f = f;
    unsigned r = v.u + 0x7fffu + ((v.u >> 16) & 1u);
    return (short)(r >> 16);
}

__device__ __forceinline__ floatx4 mfma16(short8 a, short8 b, floatx4 c) {
    return __builtin_amdgcn_mfma_f32_16x16x32_bf16(a, b, c, 0, 0, 0);
}

// ---------------- convert x: fp32 -> bf16 ----------------
__global__ __launch_bounds__(256) void convert_x_kernel(const float* __restrict__ x,
                                                        short* __restrict__ xb) {
    int i = (blockIdx.x * 256 + threadIdx.x) * 4;
    float4 v = *(const float4*)(x + i);
    short4v o;
    o.x = f2bf(v.x); o.y = f2bf(v.y); o.z = f2bf(v.z); o.w = f2bf(v.w);
    *(short4v*)(xb + i) = o;
}

// ---------------- transpose+convert weights: (K,N) fp32 -> (N,K) bf16 ----------------
__global__ __launch_bounds__(256) void wt_kernel(const float* __restrict__ w0, const float* __restrict__ w1,
                                                 const float* __restrict__ w2, const float* __restrict__ w3,
                                                 short* __restrict__ o0, short* __restrict__ o1,
                                                 short* __restrict__ o2, short* __restrict__ o3) {
    const float* src; short* dst;
    switch (blockIdx.z) {
        case 0: src = w0; dst = o0; break;
        case 1: src = w1; dst = o1; break;
        case 2: src = w2; dst = o2; break;
        default: src = w3; dst = o3; break;
    }
    __shared__ float tile[32][33];
    int tx = threadIdx.x, ty = threadIdx.y;
    int c = blockIdx.x * 32 + tx;
    int r0 = blockIdx.y * 32;
#pragma unroll
    for (int i = 0; i < 4; i++)
        tile[ty + i * 8][tx] = src[(size_t)(r0 + ty + i * 8) * DMODEL + c];
    __syncthreads();
    int co = blockIdx.y * 32 + tx;
    int ro = blockIdx.x * 32;
#pragma unroll
    for (int i = 0; i < 4; i++)
        dst[(size_t)(ro + ty + i * 8) * DMODEL + co] = f2bf(tile[tx][ty + i * 8]);
}

// ---------------- shared GEMM mainloop: C(128x128) = A(MxK) * Bt(NxK)^T ----------------
__device__ __forceinline__ void gemm_core(const short* __restrict__ A,
                                          const short* __restrict__ Bt,
                                          int m0, int n0,
                                          short (*As)[72], short (*Bs)[72],
                                          floatx4 acc[4][4]) {
    const int t = threadIdx.x;
    const int lane = t & 63;
    const int w = t >> 6;
    const int wr = w >> 1, wc = w & 1;
    const int l15 = lane & 15, lhi = lane >> 4;
    const int lrow = t >> 3;        // 0..31
    const int lcol = (t & 7) * 8;   // 0..56

    for (int k0 = 0; k0 < DMODEL; k0 += 64) {
#pragma unroll
        for (int i = 0; i < 4; i++) {
            int row = i * 32 + lrow;
            *(short8*)&As[row][lcol] = *(const short8*)(A + (size_t)(m0 + row) * DMODEL + k0 + lcol);
            *(short8*)&Bs[row][lcol] = *(const short8*)(Bt + (size_t)(n0 + row) * DMODEL + k0 + lcol);
        }
        __syncthreads();
#pragma unroll
        for (int kk = 0; kk < 64; kk += 32) {
            short8 af[4], bf[4];
#pragma unroll
            for (int i = 0; i < 4; i++)
                af[i] = *(short8*)&As[wr * 64 + i * 16 + l15][kk + lhi * 8];
#pragma unroll
            for (int j = 0; j < 4; j++)
                bf[j] = *(short8*)&Bs[wc * 64 + j * 16 + l15][kk + lhi * 8];
#pragma unroll
            for (int i = 0; i < 4; i++)
#pragma unroll
                for (int j = 0; j < 4; j++)
                    acc[i][j] = mfma16(af[i], bf[j], acc[i][j]);
        }
        __syncthreads();
    }
}

// ---------------- QKV GEMM: out layouts per-head; V transposed ----------------
__global__ __launch_bounds__(256) void gemm_qkv(const short* __restrict__ A,
                                                const short* __restrict__ wq, const short* __restrict__ wk,
                                                const short* __restrict__ wv,
                                                const float* __restrict__ bq, const float* __restrict__ bk,
                                                const float* __restrict__ bv,
                                                short* __restrict__ qh, short* __restrict__ kh,
                                                short* __restrict__ vt) {
    __shared__ short As[128][72];
    __shared__ short Bs[128][72];
    const int mode = blockIdx.z;
    const short* Bt = (mode == 0) ? wq : (mode == 1) ? wk : wv;
    const float* bias = (mode == 0) ? bq : (mode == 1) ? bk : bv;

    floatx4 acc[4][4];
    floatx4 z = {0.f, 0.f, 0.f, 0.f};
#pragma unroll
    for (int i = 0; i < 4; i++)
#pragma unroll
        for (int j = 0; j < 4; j++) acc[i][j] = z;

    const int m0 = blockIdx.y * 128, n0 = blockIdx.x * 128;
    gemm_core(A, Bt, m0, n0, As, Bs, acc);

    const int lane = threadIdx.x & 63;
    const int w = threadIdx.x >> 6;
    const int wr = w >> 1, wc = w & 1;
    const int l15 = lane & 15, lhi = lane >> 4;
#pragma unroll
    for (int i = 0; i < 4; i++) {
#pragma unroll
        for (int j = 0; j < 4; j++) {
            int n = n0 + wc * 64 + j * 16 + l15;
            float bv_ = bias[n];
            int h = n >> 6, d = n & 63;
            int mbase = m0 + wr * 64 + i * 16 + (lhi << 2);
#pragma unroll
            for (int r = 0; r < 4; r++) {
                int m = mbase + r;
                int b = m >> 11, s = m & 2047;
                short val = f2bf(acc[i][j][r] + bv_);
                if (mode == 0)
                    qh[((size_t)(b * NH + h) * S_LEN + s) * DEPTH + d] = val;
                else if (mode == 1)
                    kh[((size_t)(b * NH + h) * S_LEN + s) * DEPTH + d] = val;
                else
                    vt[((size_t)(b * NH + h) * DEPTH + d) * S_LEN + s] = val;
            }
        }
    }
}

// ---------------- output projection GEMM: fp32 out ----------------
__global__ __launch_bounds__(256) void gemm_out(const short* __restrict__ A,
                                                const short* __restrict__ Bt,
                                                const float* __restrict__ bias,
                                                float* __restrict__ out) {
    __shared__ short As[128][72];
    __shared__ short Bs[128][72];
    floatx4 acc[4][4];
    floatx4 z = {0.f, 0.f, 0.f, 0.f};
#pragma unroll
    for (int i = 0; i < 4; i++)
#pragma unroll
        for (int j = 0; j < 4; j++) acc[i][j] = z;

    const int m0 = blockIdx.y * 128, n0 = blockIdx.x * 128;
    gemm_core(A, Bt, m0, n0, As, Bs, acc);

    const int lane = threadIdx.x & 63;
    const int w = threadIdx.x >> 6;
    const int wr = w >> 1, wc = w & 1;
    const int l15 = lane & 15, lhi = lane >> 4;
#pragma unroll
    for (int i = 0; i < 4; i++) {
#pragma unroll
        for (int j = 0; j < 4; j++) {
            int n = n0 + wc * 64 + j * 16 + l15;
            float bv_ = bias[n];
            int mbase = m0 + wr * 64 + i * 16 + (lhi << 2);
#pragma unroll
            for (int r = 0; r < 4; r++) {
                int m = mbase + r;
                out[(size_t)m * DMODEL + n] = acc[i][j][r] + bv_;
            }
        }
    }
}

// ---------------- flash attention: 4 waves/block, 16 q-rows/wave, KV-tile 64 ----------------
__global__ __launch_bounds__(256) void attn_kernel(const short* __restrict__ qh,
                                                   const short* __restrict__ kh,
                                                   const short* __restrict__ vt,
                                                   const float* __restrict__ pm,
                                                   short* __restrict__ ao) {
    __shared__ short p_lds[4][16][72];
    const int lane = threadIdx.x & 63;
    const int wid = threadIdx.x >> 6;
    const int bh = blockIdx.y;
    const int b = bh >> 4, h = bh & 15;
    const int q0 = blockIdx.x * 64 + wid * 16;
    const short* qb = qh + (size_t)bh * S_LEN * DEPTH;
    const short* kb = kh + (size_t)bh * S_LEN * DEPTH;
    const short* vb = vt + (size_t)bh * DEPTH * S_LEN;
    const float* pmb = pm + b * S_LEN;
    const int l15 = lane & 15, lhi = lane >> 4;

    short8 qf[2];
#pragma unroll
    for (int c = 0; c < 2; c++)
        qf[c] = *(const short8*)(qb + (size_t)(q0 + l15) * DEPTH + c * 32 + lhi * 8);

    float m_r[4], l_r[4];
    floatx4 oacc[4];
    floatx4 z = {0.f, 0.f, 0.f, 0.f};
#pragma unroll
    for (int r = 0; r < 4; r++) { m_r[r] = -INFINITY; l_r[r] = 0.f; }
#pragma unroll
    for (int dt = 0; dt < 4; dt++) oacc[dt] = z;

    const int jend = q0 + 15;
    for (int j0 = 0; j0 <= jend; j0 += 64) {
        floatx4 sacc[4];
#pragma unroll
        for (int tt = 0; tt < 4; tt++) sacc[tt] = z;
#pragma unroll
        for (int tt = 0; tt < 4; tt++) {
#pragma unroll
            for (int c = 0; c < 2; c++) {
                short8 kf = *(const short8*)(kb + (size_t)(j0 + tt * 16 + l15) * DEPTH + c * 32 + lhi * 8);
                sacc[tt] = mfma16(qf[c], kf, sacc[tt]);
            }
        }
        // scale + masks
        float sv[4][4];
#pragma unroll
        for (int tt = 0; tt < 4; tt++) {
            int col = j0 + tt * 16 + l15;
            float maskadd = (1.0f - pmb[col]) * (-1e9f);
#pragma unroll
            for (int r = 0; r < 4; r++) {
                int row = q0 + lhi * 4 + r;
                float v = sacc[tt][r] * 0.125f + maskadd;
                if (col > row) v += -1e9f;
                sv[tt][r] = v;
            }
        }
        // online softmax per row
#pragma unroll
        for (int r = 0; r < 4; r++) {
            float mx = fmaxf(fmaxf(sv[0][r], sv[1][r]), fmaxf(sv[2][r], sv[3][r]));
#pragma unroll
            for (int off = 1; off < 16; off <<= 1)
                mx = fmaxf(mx, __shfl_xor(mx, off, 64));
            float mnew = fmaxf(m_r[r], mx);
            float sf = __expf(m_r[r] - mnew);
            float rs = 0.f;
#pragma unroll
            for (int tt = 0; tt < 4; tt++) {
                float p = __expf(sv[tt][r] - mnew);
                sv[tt][r] = p;
                rs += p;
            }
#pragma unroll
            for (int off = 1; off < 16; off <<= 1)
                rs += __shfl_xor(rs, off, 64);
            l_r[r] = l_r[r] * sf + rs;
            m_r[r] = mnew;
#pragma unroll
            for (int dt = 0; dt < 4; dt++) oacc[dt][r] *= sf;
        }
        // P -> LDS (bf16), relayout C->A fragment
#pragma unroll
        for (int tt = 0; tt < 4; tt++)
#pragma unroll
            for (int r = 0; r < 4; r++)
                p_lds[wid][lhi * 4 + r][tt * 16 + l15] = f2bf(sv[tt][r]);
        // PV
#pragma unroll
        for (int kc = 0; kc < 2; kc++) {
            short8 pf = *(short8*)&p_lds[wid][l15][kc * 32 + lhi * 8];
#pragma unroll
            for (int dt = 0; dt < 4; dt++) {
                short8 vf = *(const short8*)(vb + (size_t)(dt * 16 + l15) * S_LEN + j0 + kc * 32 + lhi * 8);
                oacc[dt] = mfma16(pf, vf, oacc[dt]);
            }
        }
    }
    // epilogue
#pragma unroll
    for (int dt = 0; dt < 4; dt++) {
        int d = dt * 16 + l15;
#pragma unroll
        for (int r = 0; r < 4; r++) {
            int row = q0 + lhi * 4 + r;
            float o = oacc[dt][r] / l_r[r];
            ao[((size_t)(b * S_LEN) + row) * DMODEL + h * DEPTH + d] = f2bf(o);
        }
    }
}

extern "C" void kernel_launch(void* const* d_in, const int* in_sizes, int n_in,
                              void* d_out, int out_size, void* d_ws, size_t ws_size,
                              hipStream_t stream) {
    const float* x    = (const float*)d_in[0];
    const float* pm   = (const float*)d_in[1];
    const float* wq_w = (const float*)d_in[2];
    const float* wq_b = (const float*)d_in[3];
    const float* wk_w = (const float*)d_in[4];
    const float* wk_b = (const float*)d_in[5];
    const float* wv_w = (const float*)d_in[6];
    const float* wv_b = (const float*)d_in[7];
    const float* wo_w = (const float*)d_in[8];
    const float* wo_b = (const float*)d_in[9];
    float* out = (float*)d_out;

    char* ws = (char*)d_ws;
    const size_t MB = 1024 * 1024;
    short* xb  = (short*)(ws);            // 8 MB : x bf16 (4096x1024)
    short* wqb = (short*)(ws + 8 * MB);   // 2 MB : wq^T bf16
    short* wkb = (short*)(ws + 10 * MB);
    short* wvb = (short*)(ws + 12 * MB);
    short* wob = (short*)(ws + 14 * MB);
    short* qh  = (short*)(ws + 16 * MB);  // 8 MB : Q (B,H,S,depth) bf16
    short* kh  = (short*)(ws + 24 * MB);  // 8 MB : K (B,H,S,depth) bf16
    short* vt  = (short*)(ws + 32 * MB);  // 8 MB : V^T (B,H,depth,S) bf16
    short* ao  = (short*)(ws + 40 * MB);  // 8 MB : attn out (B,S,D) bf16

    convert_x_kernel<<<4096, 256, 0, stream>>>(x, xb);
    wt_kernel<<<dim3(32, 32, 4), dim3(32, 8), 0, stream>>>(wq_w, wk_w, wv_w, wo_w,
                                                           wqb, wkb, wvb, wob);
    gemm_qkv<<<dim3(8, 32, 3), 256, 0, stream>>>(xb, wqb, wkb, wvb, wq_b, wk_b, wv_b,
                                                 qh, kh, vt);
    attn_kernel<<<dim3(32, 32), 256, 0, stream>>>(qh, kh, vt, pm, ao);
    gemm_out<<<dim3(8, 32), 256, 0, stream>>>(ao, wob, wo_b, out);
}

// Round 3
// 265.790 us; speedup vs baseline: 1.2069x; 1.2069x over previous
//
#include <hip/hip_runtime.h>
#include <math.h>

#define S_LEN 2048
#define DMODEL 1024
#define NH 16
#define DEPTH 64
#define BATCH 2
#define MTOT (BATCH * S_LEN) // 4096

typedef __attribute__((ext_vector_type(8))) short short8;
typedef __attribute__((ext_vector_type(4))) short short4v;
typedef __attribute__((ext_vector_type(4))) float floatx4;

__device__ __forceinline__ short f2bf(float f) {
    union { float f; unsigned u; } v; v.f = f;
    unsigned r = v.u + 0x7fffu + ((v.u >> 16) & 1u);
    return (short)(r >> 16);
}

__device__ __forceinline__ floatx4 mfma16(short8 a, short8 b, floatx4 c) {
    return __builtin_amdgcn_mfma_f32_16x16x32_bf16(a, b, c, 0, 0, 0);
}

// K=16 bf16 MFMA: A/B are 4 bf16 per lane (2 VGPRs). A: row=lane&15, k=(lane>>4)*4+e.
#if __has_builtin(__builtin_amdgcn_mfma_f32_16x16x16bf16_1k)
__device__ __forceinline__ floatx4 mfma16k16(short4v a, short4v b, floatx4 c) {
    return __builtin_amdgcn_mfma_f32_16x16x16bf16_1k(a, b, c, 0, 0, 0);
}
#else
__device__ __forceinline__ floatx4 mfma16k16(short4v a, short4v b, floatx4 c) {
    asm volatile("v_mfma_f32_16x16x16_bf16 %0, %1, %2, %0\n\ts_nop 7\n\ts_nop 7"
                 : "+v"(c) : "v"(a), "v"(b));
    return c;
}
#endif

// ---------------- convert x: fp32 -> bf16 ----------------
__global__ __launch_bounds__(256) void convert_x_kernel(const float* __restrict__ x,
                                                        short* __restrict__ xb) {
    int i = (blockIdx.x * 256 + threadIdx.x) * 4;
    float4 v = *(const float4*)(x + i);
    short4v o;
    o.x = f2bf(v.x); o.y = f2bf(v.y); o.z = f2bf(v.z); o.w = f2bf(v.w);
    *(short4v*)(xb + i) = o;
}

// ---------------- transpose+convert weights: (K,N) fp32 -> (N,K) bf16 ----------------
__global__ __launch_bounds__(256) void wt_kernel(const float* __restrict__ w0, const float* __restrict__ w1,
                                                 const float* __restrict__ w2, const float* __restrict__ w3,
                                                 short* __restrict__ o0, short* __restrict__ o1,
                                                 short* __restrict__ o2, short* __restrict__ o3) {
    const float* src; short* dst;
    switch (blockIdx.z) {
        case 0: src = w0; dst = o0; break;
        case 1: src = w1; dst = o1; break;
        case 2: src = w2; dst = o2; break;
        default: src = w3; dst = o3; break;
    }
    __shared__ float tile[32][33];
    int tx = threadIdx.x, ty = threadIdx.y;
    int c = blockIdx.x * 32 + tx;
    int r0 = blockIdx.y * 32;
#pragma unroll
    for (int i = 0; i < 4; i++)
        tile[ty + i * 8][tx] = src[(size_t)(r0 + ty + i * 8) * DMODEL + c];
    __syncthreads();
    int co = blockIdx.y * 32 + tx;
    int ro = blockIdx.x * 32;
#pragma unroll
    for (int i = 0; i < 4; i++)
        dst[(size_t)(ro + ty + i * 8) * DMODEL + co] = f2bf(tile[tx][ty + i * 8]);
}

// ---------------- shared GEMM mainloop: C(128x128) = A(MxK) * Bt(NxK)^T ----------------
__device__ __forceinline__ void gemm_core(const short* __restrict__ A,
                                          const short* __restrict__ Bt,
                                          int m0, int n0,
                                          short (*As)[72], short (*Bs)[72],
                                          floatx4 acc[4][4]) {
    const int t = threadIdx.x;
    const int lane = t & 63;
    const int w = t >> 6;
    const int wr = w >> 1, wc = w & 1;
    const int l15 = lane & 15, lhi = lane >> 4;
    const int lrow = t >> 3;        // 0..31
    const int lcol = (t & 7) * 8;   // 0..56

    for (int k0 = 0; k0 < DMODEL; k0 += 64) {
#pragma unroll
        for (int i = 0; i < 4; i++) {
            int row = i * 32 + lrow;
            *(short8*)&As[row][lcol] = *(const short8*)(A + (size_t)(m0 + row) * DMODEL + k0 + lcol);
            *(short8*)&Bs[row][lcol] = *(const short8*)(Bt + (size_t)(n0 + row) * DMODEL + k0 + lcol);
        }
        __syncthreads();
#pragma unroll
        for (int kk = 0; kk < 64; kk += 32) {
            short8 af[4], bf[4];
#pragma unroll
            for (int i = 0; i < 4; i++)
                af[i] = *(short8*)&As[wr * 64 + i * 16 + l15][kk + lhi * 8];
#pragma unroll
            for (int j = 0; j < 4; j++)
                bf[j] = *(short8*)&Bs[wc * 64 + j * 16 + l15][kk + lhi * 8];
#pragma unroll
            for (int i = 0; i < 4; i++)
#pragma unroll
                for (int j = 0; j < 4; j++)
                    acc[i][j] = mfma16(af[i], bf[j], acc[i][j]);
        }
        __syncthreads();
    }
}

// ---------------- QKV GEMM: out layouts per-head; V transposed ----------------
__global__ __launch_bounds__(256) void gemm_qkv(const short* __restrict__ A,
                                                const short* __restrict__ wq, const short* __restrict__ wk,
                                                const short* __restrict__ wv,
                                                const float* __restrict__ bq, const float* __restrict__ bk,
                                                const float* __restrict__ bv,
                                                short* __restrict__ qh, short* __restrict__ kh,
                                                short* __restrict__ vt) {
    __shared__ short As[128][72];
    __shared__ short Bs[128][72];
    const int mode = blockIdx.z;
    const short* Bt = (mode == 0) ? wq : (mode == 1) ? wk : wv;
    const float* bias = (mode == 0) ? bq : (mode == 1) ? bk : bv;

    floatx4 acc[4][4];
    floatx4 z = {0.f, 0.f, 0.f, 0.f};
#pragma unroll
    for (int i = 0; i < 4; i++)
#pragma unroll
        for (int j = 0; j < 4; j++) acc[i][j] = z;

    const int m0 = blockIdx.y * 128, n0 = blockIdx.x * 128;
    gemm_core(A, Bt, m0, n0, As, Bs, acc);

    const int lane = threadIdx.x & 63;
    const int w = threadIdx.x >> 6;
    const int wr = w >> 1, wc = w & 1;
    const int l15 = lane & 15, lhi = lane >> 4;
#pragma unroll
    for (int i = 0; i < 4; i++) {
#pragma unroll
        for (int j = 0; j < 4; j++) {
            int n = n0 + wc * 64 + j * 16 + l15;
            float bv_ = bias[n];
            int h = n >> 6, d = n & 63;
            int mbase = m0 + wr * 64 + i * 16 + (lhi << 2);
#pragma unroll
            for (int r = 0; r < 4; r++) {
                int m = mbase + r;
                int b = m >> 11, s = m & 2047;
                short val = f2bf(acc[i][j][r] + bv_);
                if (mode == 0)
                    qh[((size_t)(b * NH + h) * S_LEN + s) * DEPTH + d] = val;
                else if (mode == 1)
                    kh[((size_t)(b * NH + h) * S_LEN + s) * DEPTH + d] = val;
                else
                    vt[((size_t)(b * NH + h) * DEPTH + d) * S_LEN + s] = val;
            }
        }
    }
}

// ---------------- output projection GEMM: fp32 out ----------------
__global__ __launch_bounds__(256) void gemm_out(const short* __restrict__ A,
                                                const short* __restrict__ Bt,
                                                const float* __restrict__ bias,
                                                float* __restrict__ out) {
    __shared__ short As[128][72];
    __shared__ short Bs[128][72];
    floatx4 acc[4][4];
    floatx4 z = {0.f, 0.f, 0.f, 0.f};
#pragma unroll
    for (int i = 0; i < 4; i++)
#pragma unroll
        for (int j = 0; j < 4; j++) acc[i][j] = z;

    const int m0 = blockIdx.y * 128, n0 = blockIdx.x * 128;
    gemm_core(A, Bt, m0, n0, As, Bs, acc);

    const int lane = threadIdx.x & 63;
    const int w = threadIdx.x >> 6;
    const int wr = w >> 1, wc = w & 1;
    const int l15 = lane & 15, lhi = lane >> 4;
#pragma unroll
    for (int i = 0; i < 4; i++) {
#pragma unroll
        for (int j = 0; j < 4; j++) {
            int n = n0 + wc * 64 + j * 16 + l15;
            float bv_ = bias[n];
            int mbase = m0 + wr * 64 + i * 16 + (lhi << 2);
#pragma unroll
            for (int r = 0; r < 4; r++) {
                int m = mbase + r;
                out[(size_t)m * DMODEL + n] = acc[i][j][r] + bv_;
            }
        }
    }
}

// ---------------- flash attention, swapped-QK^T, fully in-register P ----------------
// No LDS, no barriers. 4 independent waves/block, 32 q-rows/wave.
// QK^T swapped (A=K,B=Q): sacc C layout col=q=lane&15, row=key=(lane>>4)*4+r.
// PV uses K=16 MFMA whose A-fragment layout (row=lane&15, k=(lane>>4)*4+e)
// EXACTLY matches sacc's layout -> P never leaves registers.
__global__ __launch_bounds__(256) void attn_kernel(const short* __restrict__ qh,
                                                   const short* __restrict__ kh,
                                                   const short* __restrict__ vt,
                                                   const float* __restrict__ pm,
                                                   short* __restrict__ ao) {
    const int lane = threadIdx.x & 63;
    const int wid = threadIdx.x >> 6;
    const int bh = blockIdx.y;
    const int b = bh >> 4, h = bh & 15;
    // balance causal-triangle work: interleave light/heavy q-tiles across blocks
    const int qt = (blockIdx.x & 1) ? (15 - (blockIdx.x >> 1)) : (blockIdx.x >> 1);
    const int qbase = qt * 128 + wid * 32;
    const short* qb = qh + (size_t)bh * S_LEN * DEPTH;
    const short* kb = kh + (size_t)bh * S_LEN * DEPTH;
    const short* vb = vt + (size_t)bh * DEPTH * S_LEN;
    const float* pmb = pm + b * S_LEN;
    const int l15 = lane & 15, lhi = lane >> 4;

    // Q fragments (B-operand of K=32 MFMA): col=q=l15, k=c*32+lhi*8
    short8 qf[2][2];
#pragma unroll
    for (int qg = 0; qg < 2; qg++)
#pragma unroll
        for (int c = 0; c < 2; c++)
            qf[qg][c] = *(const short8*)(qb + (size_t)(qbase + qg * 16 + l15) * DEPTH + c * 32 + lhi * 8);

    float m_r[2] = {-INFINITY, -INFINITY};
    float l_r[2] = {0.f, 0.f};
    floatx4 oacc[2][4];
    floatx4 z = {0.f, 0.f, 0.f, 0.f};
#pragma unroll
    for (int qg = 0; qg < 2; qg++)
#pragma unroll
        for (int dt = 0; dt < 4; dt++) oacc[qg][dt] = z;

    const int jend = qbase + 31;
    for (int j0 = 0; j0 <= jend; j0 += 64) {
        // ---- QK^T (swapped): sacc[qg][tt], col=q, row=key ----
        floatx4 sacc[2][4];
#pragma unroll
        for (int qg = 0; qg < 2; qg++)
#pragma unroll
            for (int tt = 0; tt < 4; tt++) sacc[qg][tt] = z;

        short8 kf[4][2];
#pragma unroll
        for (int tt = 0; tt < 4; tt++)
#pragma unroll
            for (int c = 0; c < 2; c++)
                kf[tt][c] = *(const short8*)(kb + (size_t)(j0 + tt * 16 + l15) * DEPTH + c * 32 + lhi * 8);
#pragma unroll
        for (int tt = 0; tt < 4; tt++)
#pragma unroll
            for (int c = 0; c < 2; c++) {
                sacc[0][tt] = mfma16(kf[tt][c], qf[0][c], sacc[0][tt]);
                sacc[1][tt] = mfma16(kf[tt][c], qf[1][c], sacc[1][tt]);
            }

        // ---- prefetch V B-fragments for K=16 PV (independent of softmax) ----
        // lane needs V[key=j0+tt*16+lhi*4+e][d=dt*16+l15] -> 4 contiguous shorts of vt
        short4v vf[4][4];
#pragma unroll
        for (int tt = 0; tt < 4; tt++)
#pragma unroll
            for (int dt = 0; dt < 4; dt++)
                vf[tt][dt] = *(const short4v*)(vb + (size_t)(dt * 16 + l15) * S_LEN + j0 + tt * 16 + lhi * 4);

        // padding-mask additive terms (same for both qg); pm is L1/L2-resident
        float pd[16];
#pragma unroll
        for (int tt = 0; tt < 4; tt++)
#pragma unroll
            for (int r = 0; r < 4; r++)
                pd[tt * 4 + r] = (1.0f - pmb[j0 + tt * 16 + lhi * 4 + r]) * (-1e9f);

#pragma unroll
        for (int qg = 0; qg < 2; qg++) {
            const int q = qbase + qg * 16 + l15;
            // ---- online softmax; q is lane-local, keys spread over lhi groups ----
            float mx = -INFINITY;
#pragma unroll
            for (int tt = 0; tt < 4; tt++)
#pragma unroll
                for (int r = 0; r < 4; r++) {
                    int key = j0 + tt * 16 + lhi * 4 + r;
                    float v = sacc[qg][tt][r] * 0.125f + pd[tt * 4 + r];
                    v = (key > q) ? v - 1e9f : v;
                    sacc[qg][tt][r] = v;
                    mx = fmaxf(mx, v);
                }
            mx = fmaxf(mx, __shfl_xor(mx, 16, 64));
            mx = fmaxf(mx, __shfl_xor(mx, 32, 64));
            float mnew = fmaxf(m_r[qg], mx);
            float sf = __expf(m_r[qg] - mnew);
            m_r[qg] = mnew;
            float rs = 0.f;
#pragma unroll
            for (int tt = 0; tt < 4; tt++)
#pragma unroll
                for (int r = 0; r < 4; r++) {
                    float p = __expf(sacc[qg][tt][r] - mnew);
                    sacc[qg][tt][r] = p;
                    rs += p;
                }
            rs += __shfl_xor(rs, 16, 64);
            rs += __shfl_xor(rs, 32, 64);
            l_r[qg] = l_r[qg] * sf + rs;

            // rescale O accumulator: row q=lhi*4+r takes sf from lane lhi*4+r
#pragma unroll
            for (int r = 0; r < 4; r++) {
                float sfr = __shfl(sf, lhi * 4 + r, 64);
#pragma unroll
                for (int dt = 0; dt < 4; dt++) oacc[qg][dt][r] *= sfr;
            }

            // ---- PV, K=16: A = P (in-register!), B = vf ----
#pragma unroll
            for (int tt = 0; tt < 4; tt++) {
                short4v af;
                af.x = f2bf(sacc[qg][tt][0]);
                af.y = f2bf(sacc[qg][tt][1]);
                af.z = f2bf(sacc[qg][tt][2]);
                af.w = f2bf(sacc[qg][tt][3]);
#pragma unroll
                for (int dt = 0; dt < 4; dt++)
                    oacc[qg][dt] = mfma16k16(af, vf[tt][dt], oacc[qg][dt]);
            }
        }
    }

    // ---- epilogue ----
#pragma unroll
    for (int qg = 0; qg < 2; qg++) {
        float lr4[4];
#pragma unroll
        for (int r = 0; r < 4; r++)
            lr4[r] = __shfl(l_r[qg], lhi * 4 + r, 64);
#pragma unroll
        for (int dt = 0; dt < 4; dt++) {
            int d = dt * 16 + l15;
#pragma unroll
            for (int r = 0; r < 4; r++) {
                int row = qbase + qg * 16 + lhi * 4 + r;
                float o = oacc[qg][dt][r] / lr4[r];
                ao[((size_t)(b * S_LEN) + row) * DMODEL + h * DEPTH + d] = f2bf(o);
            }
        }
    }
}

extern "C" void kernel_launch(void* const* d_in, const int* in_sizes, int n_in,
                              void* d_out, int out_size, void* d_ws, size_t ws_size,
                              hipStream_t stream) {
    const float* x    = (const float*)d_in[0];
    const float* pm   = (const float*)d_in[1];
    const float* wq_w = (const float*)d_in[2];
    const float* wq_b = (const float*)d_in[3];
    const float* wk_w = (const float*)d_in[4];
    const float* wk_b = (const float*)d_in[5];
    const float* wv_w = (const float*)d_in[6];
    const float* wv_b = (const float*)d_in[7];
    const float* wo_w = (const float*)d_in[8];
    const float* wo_b = (const float*)d_in[9];
    float* out = (float*)d_out;

    char* ws = (char*)d_ws;
    const size_t MB = 1024 * 1024;
    short* xb  = (short*)(ws);            // 8 MB : x bf16 (4096x1024)
    short* wqb = (short*)(ws + 8 * MB);   // 2 MB : wq^T bf16
    short* wkb = (short*)(ws + 10 * MB);
    short* wvb = (short*)(ws + 12 * MB);
    short* wob = (short*)(ws + 14 * MB);
    short* qh  = (short*)(ws + 16 * MB);  // 8 MB : Q (B,H,S,depth) bf16
    short* kh  = (short*)(ws + 24 * MB);  // 8 MB : K (B,H,S,depth) bf16
    short* vt  = (short*)(ws + 32 * MB);  // 8 MB : V^T (B,H,depth,S) bf16
    short* ao  = (short*)(ws + 40 * MB);  // 8 MB : attn out (B,S,D) bf16

    convert_x_kernel<<<4096, 256, 0, stream>>>(x, xb);
    wt_kernel<<<dim3(32, 32, 4), dim3(32, 8), 0, stream>>>(wq_w, wk_w, wv_w, wo_w,
                                                           wqb, wkb, wvb, wob);
    gemm_qkv<<<dim3(8, 32, 3), 256, 0, stream>>>(xb, wqb, wkb, wvb, wq_b, wk_b, wv_b,
                                                 qh, kh, vt);
    attn_kernel<<<dim3(16, 32), 256, 0, stream>>>(qh, kh, vt, pm, ao);
    gemm_out<<<dim3(8, 32), 256, 0, stream>>>(ao, wob, wo_b, out);
}